// Round 5
// baseline (6363.586 us; speedup 1.0000x reference)
//
#include <hip/hip_runtime.h>
#include <hip/hip_bf16.h>

#define N_NODES 10000
#define N_EDGES 320000
#define D_NODE 32
#define D_RAD 8
#define D_SPH 9
#define LAT 64
#define NHEAD 8
#define NL 2
#define GEN_W 280
#define WN_ENV 24

#define RS136 0.08574929257125442f   // 136^-0.5
#define RS8   0.35355339059327373f   // 8^-0.5

__device__ __forceinline__ int irrep_of(int d){ return (d==0)?0:((d<4)?1:2); }

__device__ __forceinline__ float wave_sum(float v){
  #pragma unroll
  for (int off=32; off; off>>=1) v += __shfl_xor(v, off);
  return v;
}

__device__ __forceinline__ float ln64(float a, float gj, float bj){
  float mu = wave_sum(a) * (1.f/64.f);
  float va = wave_sum(a*a) * (1.f/64.f) - mu*mu;
  return (a - mu) * rsqrtf(va + 1e-5f) * gj + bj;
}

__device__ __forceinline__ void atomicMaxF(float* addr, float v){
  if (v >= 0.f) atomicMax((int*)addr, __float_as_int(v));
  else          atomicMin((unsigned int*)addr, __float_as_uint(v));
}

__global__ void fill_neg_inf(float* p, int n){
  int i = blockIdx.x*blockDim.x + threadIdx.x;
  if (i < n) p[i] = __uint_as_float(0xff800000u);
}

// K1: pn = na@W_node, pc = na@W_center
__global__ void k_node_proj(const float* __restrict__ na,
                            const float* __restrict__ Wn,
                            const float* __restrict__ Wc,
                            float* __restrict__ pn, float* __restrict__ pc){
  int idx = blockIdx.x*blockDim.x + threadIdx.x;
  int n = idx >> 6, j = idx & 63;
  if (n >= N_NODES) return;
  float an = 0.f, ac = 0.f;
  #pragma unroll
  for (int k = 0; k < D_NODE; k++){
    float a = na[n*D_NODE + k];
    an += a * Wn[k*LAT + j];
    ac += a * Wc[k*LAT + j];
  }
  pn[idx] = an; pc[idx] = ac;
}

// K2: pe = pn[nb] * (phi@W_edge); m_node = segsum(pe)
__global__ void k_edge_msg(const float* __restrict__ phi,
                           const float* __restrict__ We,
                           const int* __restrict__ ec, const int* __restrict__ en,
                           const float* __restrict__ pn, float* __restrict__ mnode){
  int idx = blockIdx.x*blockDim.x + threadIdx.x;
  int e = idx >> 6, j = idx & 63;
  float d = 0.f;
  #pragma unroll
  for (int k = 0; k < D_RAD; k++) d += phi[e*D_RAD + k] * We[k*LAT + j];
  float pe = pn[en[e]*LAT + j] * d;
  atomicAdd(&mnode[ec[e]*LAT + j], pe);
}

// K3: h0 = h = LN([pc, m_node]@W_concat)
__global__ void k_node_h(const float* __restrict__ pc, const float* __restrict__ mnode,
                         const float* __restrict__ Wcat,
                         const float* __restrict__ g, const float* __restrict__ b,
                         float* __restrict__ h0, float* __restrict__ h){
  int n = blockIdx.x*(blockDim.x >> 6) + (threadIdx.x >> 6);
  int j = threadIdx.x & 63;
  if (n >= N_NODES) return;
  float acc = 0.f;
  for (int k = 0; k < LAT; k++) acc += pc[n*LAT + k] * Wcat[k*LAT + j];
  for (int k = 0; k < LAT; k++) acc += mnode[n*LAT + k] * Wcat[(LAT + k)*LAT + j];
  float v = ln64(acc, g[j], b[j]);
  h0[n*LAT + j] = v; h[n*LAT + j] = v;
}

// K4: t = LN(tcat@Wtcat); store T; edge_out; w0 scatter. 512 thr, 4 edges/wave.
// LDS: 34.8+16+6+6+16 = 78.8 KB -> 2 blocks/CU, 16 waves/CU.
__global__ void __launch_bounds__(512) k_edge_tij(const float* __restrict__ h0,
                           const float* __restrict__ phi,
                           const float* __restrict__ sph,
                           const float* __restrict__ Wtcat,
                           const float* __restrict__ lg, const float* __restrict__ lb,
                           const float* __restrict__ Wtij,
                           const float* __restrict__ Wt0,
                           const float* __restrict__ Wh0,
                           const int* __restrict__ ec, const int* __restrict__ en,
                           float* __restrict__ T, float* __restrict__ Xacc,
                           float* __restrict__ edge_out){
  __shared__ float swt[136*64];
  __shared__ float swij[64*64];
  __shared__ float sw0[64*24], sh0[64*24];
  __shared__ float stg[8][4][128];
  for (int i = threadIdx.x; i < 136*64; i += 512) swt[i] = Wtcat[i];
  for (int i = threadIdx.x; i < 64*64;  i += 512) swij[i] = Wtij[i];
  for (int i = threadIdx.x; i < 64*24;  i += 512){ sw0[i] = Wt0[i]; sh0[i] = Wh0[i]; }
  __syncthreads();
  const int j = threadIdx.x & 63, lw = threadIdx.x >> 6;
  const float gj = lg[j], bj = lb[j];
  int wid = blockIdx.x*8 + lw, nw = gridDim.x*8;
  const int jc = (j < WN_ENV) ? j : 0;
  for (int q = wid; q < N_EDGES/4; q += nw){
    int c[4], nb[4];
    #pragma unroll
    for (int x = 0; x < 4; x++){ c[x] = ec[4*q+x]; nb[x] = en[4*q+x]; }
    #pragma unroll
    for (int x = 0; x < 4; x++){
      stg[lw][x][j]      = h0[c[x]*LAT + j];
      stg[lw][x][64 + j] = h0[nb[x]*LAT + j];
    }
    __threadfence_block();
    float a0v=0.f, a1v=0.f, a2v=0.f, a3v=0.f;
    for (int k = 0; k < 64; k += 4){
      float4 c0 = *(const float4*)&stg[lw][0][k], c1 = *(const float4*)&stg[lw][1][k];
      float4 c2 = *(const float4*)&stg[lw][2][k], c3 = *(const float4*)&stg[lw][3][k];
      float4 d0 = *(const float4*)&stg[lw][0][64+k], d1 = *(const float4*)&stg[lw][1][64+k];
      float4 d2 = *(const float4*)&stg[lw][2][64+k], d3 = *(const float4*)&stg[lw][3][64+k];
      float ca0[4]={c0.x,c0.y,c0.z,c0.w}, ca1[4]={c1.x,c1.y,c1.z,c1.w};
      float ca2[4]={c2.x,c2.y,c2.z,c2.w}, ca3[4]={c3.x,c3.y,c3.z,c3.w};
      float da0[4]={d0.x,d0.y,d0.z,d0.w}, da1[4]={d1.x,d1.y,d1.z,d1.w};
      float da2[4]={d2.x,d2.y,d2.z,d2.w}, da3[4]={d3.x,d3.y,d3.z,d3.w};
      #pragma unroll
      for (int kk = 0; kk < 4; kk++){
        float w1 = swt[(k+kk)*64 + j];
        float w2 = swt[(64+k+kk)*64 + j];
        a0v += ca0[kk]*w1 + da0[kk]*w2;
        a1v += ca1[kk]*w1 + da1[kk]*w2;
        a2v += ca2[kk]*w1 + da2[kk]*w2;
        a3v += ca3[kk]*w1 + da3[kk]*w2;
      }
    }
    #pragma unroll
    for (int k = 0; k < D_RAD; k++){
      float w = swt[(128+k)*64 + j];
      a0v += phi[(long)(4*q+0)*D_RAD + k]*w;
      a1v += phi[(long)(4*q+1)*D_RAD + k]*w;
      a2v += phi[(long)(4*q+2)*D_RAD + k]*w;
      a3v += phi[(long)(4*q+3)*D_RAD + k]*w;
    }
    float t0 = ln64(a0v*RS136, gj, bj), t1 = ln64(a1v*RS136, gj, bj);
    float t2 = ln64(a2v*RS136, gj, bj), t3 = ln64(a3v*RS136, gj, bj);
    T[(long)(4*q+0)*LAT + j] = t0; T[(long)(4*q+1)*LAT + j] = t1;
    T[(long)(4*q+2)*LAT + j] = t2; T[(long)(4*q+3)*LAT + j] = t3;
    __threadfence_block();
    stg[lw][0][j] = t0; stg[lw][1][j] = t1; stg[lw][2][j] = t2; stg[lw][3][j] = t3;
    __threadfence_block();
    float eo[4] = {0,0,0,0}, aa[4] = {0,0,0,0}, bb[4] = {0,0,0,0};
    for (int k = 0; k < 64; k += 4){
      float4 t0v = *(const float4*)&stg[lw][0][k], t1v = *(const float4*)&stg[lw][1][k];
      float4 t2v = *(const float4*)&stg[lw][2][k], t3v = *(const float4*)&stg[lw][3][k];
      float4 d0 = *(const float4*)&stg[lw][0][64+k], d1 = *(const float4*)&stg[lw][1][64+k];
      float4 d2 = *(const float4*)&stg[lw][2][64+k], d3 = *(const float4*)&stg[lw][3][64+k];
      float ta[4][4] = {{t0v.x,t0v.y,t0v.z,t0v.w},{t1v.x,t1v.y,t1v.z,t1v.w},
                        {t2v.x,t2v.y,t2v.z,t2v.w},{t3v.x,t3v.y,t3v.z,t3v.w}};
      float da[4][4] = {{d0.x,d0.y,d0.z,d0.w},{d1.x,d1.y,d1.z,d1.w},
                        {d2.x,d2.y,d2.z,d2.w},{d3.x,d3.y,d3.z,d3.w}};
      #pragma unroll
      for (int kk = 0; kk < 4; kk++){
        float wij = swij[(k+kk)*64 + j];
        float w0w = sw0[(k+kk)*24 + jc];
        float h0w = sh0[(k+kk)*24 + jc];
        #pragma unroll
        for (int x = 0; x < 4; x++){
          eo[x] += ta[x][kk]*wij;
          aa[x] += ta[x][kk]*w0w;
          bb[x] += da[x][kk]*h0w;
        }
      }
    }
    #pragma unroll
    for (int x = 0; x < 4; x++) edge_out[(long)(4*q+x)*LAT + j] = eo[x]*0.125f;
    __threadfence_block();
    #pragma unroll
    for (int x = 0; x < 4; x++) if (j < WN_ENV) stg[lw][x][j] = aa[x]*bb[x]*0.015625f;
    __threadfence_block();
    #pragma unroll
    for (int x = 0; x < 4; x++){
      long ee = 4L*q + x;
      #pragma unroll
      for (int rep = 0; rep < 2; rep++){
        int tt = j + rep*64;
        if (tt < 72){
          int m = tt/9, d = tt - m*9;
          float wv = stg[lw][x][irrep_of(d)*NHEAD + m];
          atomicAdd(&Xacc[c[x]*72 + tt], sph[ee*D_SPH + d] * wv);
        }
      }
    }
    __threadfence_block();
  }
}

// K5: X = so3_norm(Xacc)
__global__ void k_node_X0(const float* __restrict__ Xacc, float* __restrict__ X){
  int n = blockIdx.x*(blockDim.x >> 6) + (threadIdx.x >> 6);
  int j = threadIdx.x & 63;
  if (n >= N_NODES) return;
  float x0 = Xacc[n*72 + j];
  float x1 = (j < 8) ? Xacc[n*72 + 64 + j] : 0.f;
  float s0 = 0.f, s1 = 0.f, s2 = 0.f;
  { int d = j % 9; int k3 = irrep_of(d);
    if (k3 == 0) s0 = x0*x0; else if (k3 == 1) s1 = x0*x0; else s2 = x0*x0; }
  if (j < 8){ int d = (64 + j) % 9; int k3 = irrep_of(d);
    if (k3 == 0) s0 += x1*x1; else if (k3 == 1) s1 += x1*x1; else s2 += x1*x1; }
  s0 = wave_sum(s0); s1 = wave_sum(s1); s2 = wave_sum(s2);
  float sa = rsqrtf(s0*0.125f + 1e-5f), sb = rsqrtf(s1*0.125f + 1e-5f), sc = rsqrtf(s2*0.125f + 1e-5f);
  { int d = j % 9; int k3 = irrep_of(d);
    X[n*72 + j] = x0 * (k3==0 ? sa : (k3==1 ? sb : sc)); }
  if (j < 8){ int d = (64 + j) % 9; int k3 = irrep_of(d);
    X[n*72 + 64 + j] = x1 * (k3==0 ? sa : (k3==1 ? sb : sc)); }
}

// K6: attention logits + running max. 384 thr, 4 edges/wave.
// LDS: 32+32+12 = 76 KB -> 2 blocks/CU, 12 waves/CU.
__global__ void __launch_bounds__(384) k_att(const float* __restrict__ T, const float* __restrict__ h,
                     const float* __restrict__ Wq, const float* __restrict__ Wk,
                     const int* __restrict__ ec, const int* __restrict__ en,
                     float* __restrict__ att, float* __restrict__ attmax){
  __shared__ float sq[64*128], sk[64*128];
  __shared__ float stg[6][4][128];
  for (int i = threadIdx.x; i < 64*128; i += 384){ sq[i] = Wq[i]; sk[i] = Wk[i]; }
  __syncthreads();
  const int j = threadIdx.x & 63, lw = threadIdx.x >> 6;
  int wid = blockIdx.x*6 + lw, nw = gridDim.x*6;
  for (int q = wid; q < N_EDGES/4; q += nw){
    int c[4], nb[4];
    #pragma unroll
    for (int x = 0; x < 4; x++){ c[x] = ec[4*q+x]; nb[x] = en[4*q+x]; }
    #pragma unroll
    for (int x = 0; x < 4; x++){
      stg[lw][x][j]      = T[(long)(4*q+x)*LAT + j];
      stg[lw][x][64 + j] = h[nb[x]*LAT + j];
    }
    __threadfence_block();
    float qlo[4]={0,0,0,0}, qhi[4]={0,0,0,0}, klo[4]={0,0,0,0}, khi[4]={0,0,0,0};
    for (int k = 0; k < 64; k += 4){
      float4 t0v = *(const float4*)&stg[lw][0][k], t1v = *(const float4*)&stg[lw][1][k];
      float4 t2v = *(const float4*)&stg[lw][2][k], t3v = *(const float4*)&stg[lw][3][k];
      float4 h0v = *(const float4*)&stg[lw][0][64+k], h1v = *(const float4*)&stg[lw][1][64+k];
      float4 h2v = *(const float4*)&stg[lw][2][64+k], h3v = *(const float4*)&stg[lw][3][64+k];
      float ta[4][4] = {{t0v.x,t0v.y,t0v.z,t0v.w},{t1v.x,t1v.y,t1v.z,t1v.w},
                        {t2v.x,t2v.y,t2v.z,t2v.w},{t3v.x,t3v.y,t3v.z,t3v.w}};
      float ha[4][4] = {{h0v.x,h0v.y,h0v.z,h0v.w},{h1v.x,h1v.y,h1v.z,h1v.w},
                        {h2v.x,h2v.y,h2v.z,h2v.w},{h3v.x,h3v.y,h3v.z,h3v.w}};
      #pragma unroll
      for (int kk = 0; kk < 4; kk++){
        float wq0 = sq[(k+kk)*128 + j],  wq1 = sq[(k+kk)*128 + 64 + j];
        float wk0 = sk[(k+kk)*128 + j],  wk1 = sk[(k+kk)*128 + 64 + j];
        #pragma unroll
        for (int x = 0; x < 4; x++){
          qlo[x] += ta[x][kk]*wq0; qhi[x] += ta[x][kk]*wq1;
          klo[x] += ha[x][kk]*wk0; khi[x] += ha[x][kk]*wk1;
        }
      }
    }
    float plo[4], phv[4];
    #pragma unroll
    for (int x = 0; x < 4; x++){ plo[x] = qlo[x]*klo[x]; phv[x] = qhi[x]*khi[x]; }
    #pragma unroll
    for (int off = 8; off; off >>= 1){
      #pragma unroll
      for (int x = 0; x < 4; x++){
        plo[x] += __shfl_xor(plo[x], off);
        phv[x] += __shfl_xor(phv[x], off);
      }
    }
    if ((j & 15) == 0){
      int m = j >> 4;
      #pragma unroll
      for (int x = 0; x < 4; x++){
        long ee = 4L*q + x;
        float alo = 4.f*plo[x], ahi = 4.f*phv[x];
        att[ee*NHEAD + m] = alo; att[ee*NHEAD + 4 + m] = ahi;
        atomicMaxF(&attmax[c[x]*NHEAD + m], alo);
        atomicMaxF(&attmax[c[x]*NHEAD + 4 + m], ahi);
      }
    }
    __threadfence_block();
  }
}

// K7a: env cols A = [0:64)+[88:120)+[152:184). 384 thr, 4 edges/wave.
// LDS: 64 + 12 = 76 KB -> 2 blocks/CU, 12 waves/CU. X read from global in phase 2.
__global__ void __launch_bounds__(384) k_envA(const float* __restrict__ T, const float* __restrict__ h,
                     const float* __restrict__ X,
                     const float* __restrict__ Wrs, const float* __restrict__ Whj,
                     const float* __restrict__ sph,
                     const float* __restrict__ att, const float* __restrict__ attmax,
                     const int* __restrict__ ec, const int* __restrict__ en,
                     float* __restrict__ hacc, float* __restrict__ asum,
                     float* __restrict__ Xacc){
  __shared__ float srs[64*128], shw[64*128];
  __shared__ float stg[6][4][128];
  for (int i = threadIdx.x; i < 64*128; i += 384){
    int k = i >> 7, s = i & 127;
    int cc = s + (s < 64 ? 0 : (s < 96 ? 24 : 56));
    srs[i] = Wrs[k*GEN_W + cc];
    shw[i] = Whj[k*GEN_W + cc];
  }
  __syncthreads();
  const int j = threadIdx.x & 63, lw = threadIdx.x >> 6;
  int wid = blockIdx.x*6 + lw, nw = gridDim.x*6;
  for (int q = wid; q < N_EDGES/4; q += nw){
    int c[4], nb[4];
    #pragma unroll
    for (int x = 0; x < 4; x++){ c[x] = ec[4*q+x]; nb[x] = en[4*q+x]; }
    #pragma unroll
    for (int x = 0; x < 4; x++){
      stg[lw][x][j]      = T[(long)(4*q+x)*LAT + j];
      stg[lw][x][64 + j] = h[nb[x]*LAT + j];
    }
    __threadfence_block();
    float rA[4]={0,0,0,0}, rB[4]={0,0,0,0}, wA[4]={0,0,0,0}, wB[4]={0,0,0,0};
    for (int k = 0; k < 64; k += 4){
      float4 t0v = *(const float4*)&stg[lw][0][k], t1v = *(const float4*)&stg[lw][1][k];
      float4 t2v = *(const float4*)&stg[lw][2][k], t3v = *(const float4*)&stg[lw][3][k];
      float4 h0v = *(const float4*)&stg[lw][0][64+k], h1v = *(const float4*)&stg[lw][1][64+k];
      float4 h2v = *(const float4*)&stg[lw][2][64+k], h3v = *(const float4*)&stg[lw][3][64+k];
      float ta[4][4] = {{t0v.x,t0v.y,t0v.z,t0v.w},{t1v.x,t1v.y,t1v.z,t1v.w},
                        {t2v.x,t2v.y,t2v.z,t2v.w},{t3v.x,t3v.y,t3v.z,t3v.w}};
      float ha[4][4] = {{h0v.x,h0v.y,h0v.z,h0v.w},{h1v.x,h1v.y,h1v.z,h1v.w},
                        {h2v.x,h2v.y,h2v.z,h2v.w},{h3v.x,h3v.y,h3v.z,h3v.w}};
      #pragma unroll
      for (int kk = 0; kk < 4; kk++){
        float wr0 = srs[(k+kk)*128 + j], wr1 = srs[(k+kk)*128 + 64 + j];
        float wh0 = shw[(k+kk)*128 + j], wh1 = shw[(k+kk)*128 + 64 + j];
        #pragma unroll
        for (int x = 0; x < 4; x++){
          rA[x] += ta[x][kk]*wr0; rB[x] += ta[x][kk]*wr1;
          wA[x] += ha[x][kk]*wh0; wB[x] += ha[x][kk]*wh1;
        }
      }
    }
    float eA[4], eB[4];
    #pragma unroll
    for (int x = 0; x < 4; x++){
      eA[x] = rA[x]*wA[x]*0.125f; eB[x] = rB[x]*wB[x]*0.125f;
      atomicAdd(&hacc[c[x]*LAT + j], eA[x]);
    }
    __threadfence_block();
    #pragma unroll
    for (int x = 0; x < 4; x++){ stg[lw][x][j] = eA[x]; stg[lw][x][64 + j] = eB[x]; }
    __threadfence_block();
    if (j < 32){
      int x = j >> 3, m = j & 7;
      long ee = 4L*q + x;
      float ev = __expf(att[ee*NHEAD + m] - attmax[c[x]*NHEAD + m]);
      atomicAdd(&asum[c[x]*NHEAD + m], ev);
    }
    #pragma unroll
    for (int x = 0; x < 4; x++){
      long ee = 4L*q + x; int cc = c[x], nn = nb[x];
      #pragma unroll
      for (int rep = 0; rep < 2; rep++){
        int tt = j + rep*64;
        if (tt < 72){
          int m = tt/9, d = tt - m*9, k3 = irrep_of(d);
          float ds = sph[ee*D_SPH + d] * stg[lw][x][k3*8 + m];
          int sb = (k3==0) ? 24 : ((k3==1) ? 64 : 96);
          float dq = 0.f;
          #pragma unroll
          for (int i = 0; i < 4; i++) dq += X[nn*72 + i*9 + d] * stg[lw][x][sb + i*8 + m];
          float ev = __expf(att[ee*NHEAD + m] - attmax[cc*NHEAD + m]);
          atomicAdd(&Xacc[cc*72 + tt], (ds + dq*RS8) * ev);
        }
      }
    }
    __threadfence_block();
  }
}

// K7b: env cols B = [56:88)+[120:152)+[184:216). 512 thr, 4 edges/wave.
// LDS: 48 + 16 = 64 KB -> 2 blocks/CU, 16 waves/CU.
__global__ void __launch_bounds__(512) k_envB(const float* __restrict__ T, const float* __restrict__ h,
                     const float* __restrict__ X,
                     const float* __restrict__ Wrs, const float* __restrict__ Whj,
                     const float* __restrict__ att, const float* __restrict__ attmax,
                     const int* __restrict__ ec, const int* __restrict__ en,
                     float* __restrict__ Xacc){
  __shared__ float srs[64*96], shw[64*96];
  __shared__ float stg[8][4][128];
  for (int i = threadIdx.x; i < 64*96; i += 512){
    int k = i / 96, s = i - k*96;
    int cc = s + (s < 32 ? 56 : (s < 64 ? 88 : 120));
    srs[i] = Wrs[k*GEN_W + cc];
    shw[i] = Whj[k*GEN_W + cc];
  }
  __syncthreads();
  const int j = threadIdx.x & 63, lw = threadIdx.x >> 6;
  int wid = blockIdx.x*8 + lw, nw = gridDim.x*8;
  for (int q = wid; q < N_EDGES/4; q += nw){
    int c[4], nb[4];
    #pragma unroll
    for (int x = 0; x < 4; x++){ c[x] = ec[4*q+x]; nb[x] = en[4*q+x]; }
    #pragma unroll
    for (int x = 0; x < 4; x++){
      stg[lw][x][j]      = T[(long)(4*q+x)*LAT + j];
      stg[lw][x][64 + j] = h[nb[x]*LAT + j];
    }
    __threadfence_block();
    float rA[4]={0,0,0,0}, rB[4]={0,0,0,0}, wA[4]={0,0,0,0}, wB[4]={0,0,0,0};
    for (int k = 0; k < 64; k += 4){
      float4 t0v = *(const float4*)&stg[lw][0][k], t1v = *(const float4*)&stg[lw][1][k];
      float4 t2v = *(const float4*)&stg[lw][2][k], t3v = *(const float4*)&stg[lw][3][k];
      float4 h0v = *(const float4*)&stg[lw][0][64+k], h1v = *(const float4*)&stg[lw][1][64+k];
      float4 h2v = *(const float4*)&stg[lw][2][64+k], h3v = *(const float4*)&stg[lw][3][64+k];
      float ta[4][4] = {{t0v.x,t0v.y,t0v.z,t0v.w},{t1v.x,t1v.y,t1v.z,t1v.w},
                        {t2v.x,t2v.y,t2v.z,t2v.w},{t3v.x,t3v.y,t3v.z,t3v.w}};
      float ha[4][4] = {{h0v.x,h0v.y,h0v.z,h0v.w},{h1v.x,h1v.y,h1v.z,h1v.w},
                        {h2v.x,h2v.y,h2v.z,h2v.w},{h3v.x,h3v.y,h3v.z,h3v.w}};
      #pragma unroll
      for (int kk = 0; kk < 4; kk++){
        float wr0 = srs[(k+kk)*96 + j];
        float wh0 = shw[(k+kk)*96 + j];
        float wr1 = (j < 32) ? srs[(k+kk)*96 + 64 + j] : 0.f;
        float wh1 = (j < 32) ? shw[(k+kk)*96 + 64 + j] : 0.f;
        #pragma unroll
        for (int x = 0; x < 4; x++){
          rA[x] += ta[x][kk]*wr0; rB[x] += ta[x][kk]*wr1;
          wA[x] += ha[x][kk]*wh0; wB[x] += ha[x][kk]*wh1;
        }
      }
    }
    __threadfence_block();
    #pragma unroll
    for (int x = 0; x < 4; x++){
      stg[lw][x][j] = rA[x]*wA[x]*0.125f;
      if (j < 32) stg[lw][x][64 + j] = rB[x]*wB[x]*0.125f;
    }
    __threadfence_block();
    #pragma unroll
    for (int x = 0; x < 4; x++){
      long ee = 4L*q + x; int cc = c[x], nn = nb[x];
      #pragma unroll
      for (int rep = 0; rep < 2; rep++){
        int tt = j + rep*64;
        if (tt < 72){
          int m = tt/9, d = tt - m*9, k3 = irrep_of(d);
          int sb = (k3==0) ? 0 : ((k3==1) ? 32 : 64);
          float dq = 0.f;
          #pragma unroll
          for (int i = 0; i < 4; i++) dq += X[nn*72 + (i+4)*9 + d] * stg[lw][x][sb + i*8 + m];
          float ev = __expf(att[ee*NHEAD + m] - attmax[cc*NHEAD + m]);
          atomicAdd(&Xacc[cc*72 + tt], dq*RS8*ev);
        }
      }
    }
    __threadfence_block();
  }
}

// K8: h = LN(h+hacc); X = so3_norm(X + Xacc/(attsum+1e-12))
__global__ void k_node_upd(const float* __restrict__ hacc, const float* __restrict__ attsum,
                           const float* __restrict__ Xacc,
                           const float* __restrict__ lg, const float* __restrict__ lb,
                           float* __restrict__ h, float* __restrict__ X){
  int n = blockIdx.x*(blockDim.x >> 6) + (threadIdx.x >> 6);
  int j = threadIdx.x & 63;
  if (n >= N_NODES) return;
  float hv = h[n*LAT + j] + hacc[n*LAT + j];
  h[n*LAT + j] = ln64(hv, lg[j], lb[j]);

  float x0, x1 = 0.f;
  float s0 = 0.f, s1 = 0.f, s2 = 0.f;
  { int m = j/9, d = j - m*9;
    x0 = X[n*72 + j] + Xacc[n*72 + j] / (attsum[n*NHEAD + m] + 1e-12f);
    int k3 = irrep_of(d);
    if (k3 == 0) s0 = x0*x0; else if (k3 == 1) s1 = x0*x0; else s2 = x0*x0; }
  if (j < 8){ int tt = 64 + j; int m = tt/9, d = tt - m*9;
    x1 = X[n*72 + tt] + Xacc[n*72 + tt] / (attsum[n*NHEAD + m] + 1e-12f);
    int k3 = irrep_of(d);
    if (k3 == 0) s0 += x1*x1; else if (k3 == 1) s1 += x1*x1; else s2 += x1*x1; }
  s0 = wave_sum(s0); s1 = wave_sum(s1); s2 = wave_sum(s2);
  float sa = rsqrtf(s0*0.125f + 1e-5f), sb = rsqrtf(s1*0.125f + 1e-5f), sc = rsqrtf(s2*0.125f + 1e-5f);
  { int d = j % 9; int k3 = irrep_of(d);
    X[n*72 + j] = x0 * (k3==0 ? sa : (k3==1 ? sb : sc)); }
  if (j < 8){ int d = (64 + j) % 9; int k3 = irrep_of(d);
    X[n*72 + 64 + j] = x1 * (k3==0 ? sa : (k3==1 ? sb : sc)); }
}

// K9: w = h@W_hemb/8 -> (3,8,64); Xo = eq_linear(X,w); node_out
__global__ void k_node_out(const float* __restrict__ h, const float* __restrict__ X,
                           const float* __restrict__ Whemb,
                           float* __restrict__ out){
  __shared__ float sx[4][72];
  int n = blockIdx.x*(blockDim.x >> 6) + (threadIdx.x >> 6);
  int j = threadIdx.x & 63;
  int lw = threadIdx.x >> 6;
  if (n >= N_NODES) return;
  float hv = h[n*LAT + j];
  float wv[24];
  #pragma unroll
  for (int i = 0; i < 24; i++) wv[i] = 0.f;
  #pragma unroll 4
  for (int c = 0; c < LAT; c++){
    float hc = __shfl(hv, c);
    #pragma unroll
    for (int ki = 0; ki < 24; ki++)
      wv[ki] += hc * Whemb[c*1536 + ki*64 + j];
  }
  sx[lw][j] = X[n*72 + j];
  if (j < 8) sx[lw][64 + j] = X[n*72 + 64 + j];
  __threadfence_block();
  #pragma unroll
  for (int d = 0; d < 9; d++){
    int k3 = irrep_of(d);
    float acc = 0.f;
    #pragma unroll
    for (int i = 0; i < 8; i++) acc += sx[lw][i*9 + d] * wv[k3*8 + i];
    acc *= 0.125f * RS8;
    int pos;
    if (d == 0)      pos = n*576 + j;
    else if (d < 4)  pos = n*576 + 64  + j*3 + (d - 1);
    else             pos = n*576 + 256 + j*5 + (d - 4);
    out[pos] = acc;
  }
}

// ---- workspace layout (floats) — total 26.56M floats = 106.2 MB ----
static const long O_T    = 0;          // 20.48M  (E*64)
static const long O_ATT  = 20480000;   // 2.56M   (E*8) ; prologue pn/pc/mn alias here
static const long O_H0   = 23040000;   // 640k
static const long O_H    = 23680000;   // 640k
static const long O_X    = 24320000;   // 720k
static const long O_XACC = 25040000;   // 720k
static const long O_HACC = 25760000;   // 640k
static const long O_AMAX = 26400000;   // 80k
static const long O_ASUM = 26480000;   // 80k

extern "C" void kernel_launch(void* const* d_in, const int* in_sizes, int n_in,
                              void* d_out, int out_size, void* d_ws, size_t ws_size,
                              hipStream_t stream) {
  const float* na    = (const float*)d_in[0];
  const float* phi   = (const float*)d_in[1];
  const float* sph   = (const float*)d_in[2];
  const float* Wn    = (const float*)d_in[4];
  const float* Wc    = (const float*)d_in[5];
  const float* Wcat  = (const float*)d_in[6];
  const float* We    = (const float*)d_in[7];
  const float* ln0g  = (const float*)d_in[8];
  const float* ln0b  = (const float*)d_in[9];
  const float* lneg  = (const float*)d_in[10];
  const float* lneb  = (const float*)d_in[11];
  const float* Wtcat = (const float*)d_in[12];
  const float* Wt0   = (const float*)d_in[13];
  const float* Wh0   = (const float*)d_in[14];
  const float* Wrs   = (const float*)d_in[15];
  const float* Whj   = (const float*)d_in[16];
  const float* lnlg  = (const float*)d_in[17];
  const float* lnlb  = (const float*)d_in[18];
  const float* Wq    = (const float*)d_in[19];
  const float* Wk    = (const float*)d_in[20];
  const float* Whemb = (const float*)d_in[21];
  const float* Wtij  = (const float*)d_in[22];
  const int* ec = (const int*)d_in[23];
  const int* en = (const int*)d_in[24];

  float* ws   = (float*)d_ws;
  float* T    = ws + O_T;
  float* att  = ws + O_ATT;
  float* h0   = ws + O_H0;
  float* h    = ws + O_H;
  float* X    = ws + O_X;
  float* Xacc = ws + O_XACC;
  float* hacc = ws + O_HACC;
  float* amax = ws + O_AMAX;
  float* asum = ws + O_ASUM;
  float* pn   = att;
  float* pc   = att + 640000;
  float* mn   = att + 1280000;

  float* out      = (float*)d_out;
  float* edge_out = out + (long)N_NODES*576;

  hipMemsetAsync(mn,   0, 640000*sizeof(float), stream);
  hipMemsetAsync(Xacc, 0, 720000*sizeof(float), stream);

  k_node_proj<<<2500, 256, 0, stream>>>(na, Wn, Wc, pn, pc);
  k_edge_msg<<<(N_EDGES*64)/256, 256, 0, stream>>>(phi, We, ec, en, pn, mn);
  k_node_h<<<2500, 256, 0, stream>>>(pc, mn, Wcat, ln0g, ln0b, h0, h);
  k_edge_tij<<<512, 512, 0, stream>>>(h0, phi, sph, Wtcat, lneg, lneb, Wtij, Wt0, Wh0,
                                      ec, en, T, Xacc, edge_out);
  k_node_X0<<<2500, 256, 0, stream>>>(Xacc, X);

  for (int l = 0; l < NL; l++){
    hipMemsetAsync(hacc, 0, 640000*sizeof(float), stream);
    hipMemsetAsync(Xacc, 0, 720000*sizeof(float), stream);
    hipMemsetAsync(asum, 0, 80000*sizeof(float), stream);
    fill_neg_inf<<<(80000 + 255)/256, 256, 0, stream>>>(amax, 80000);

    k_att<<<512, 384, 0, stream>>>(T, h, Wq + l*64*128, Wk + l*64*128, ec, en, att, amax);
    k_envA<<<512, 384, 0, stream>>>(T, h, X, Wrs + l*64*GEN_W, Whj + l*64*GEN_W, sph,
                                    att, amax, ec, en, hacc, asum, Xacc);
    k_envB<<<512, 512, 0, stream>>>(T, h, X, Wrs + l*64*GEN_W, Whj + l*64*GEN_W,
                                    att, amax, ec, en, Xacc);
    k_node_upd<<<2500, 256, 0, stream>>>(hacc, asum, Xacc, lnlg + l*64, lnlb + l*64, h, X);
  }

  k_node_out<<<2500, 256, 0, stream>>>(h, X, Whemb, out);
}